// Round 14
// baseline (8074.393 us; speedup 1.0000x reference)
//
#include <hip/hip_runtime.h>
#include <hip/hip_bf16.h>
#include <cstdio>
#include <cstddef>

#define B_    16
#define FIN_  128
#define N_    2048
#define K_    10
#define EPS_  1e-5f
#define SLOPE_ 0.01f

// ---- stats region layout (floats) ----
constexpr int SUM_F=0,   SS_F=16,   SUM_X=32,  SS_X=48;
constexpr int SUM_A1=64, SS_A1=128, SUM_A2=192,SS_A2=448;
constexpr int SUM_I=704, SS_I=1216, SUM_O=1728,SS_O=1984;
constexpr int SCALE_F=2240, SHIFT_F=2256, SCALE_X=2272, SHIFT_X=2288;
constexpr int SCALE_A1=2304, SHIFT_A1=2368, SCALE_A2=2432, SHIFT_A2=2688;
constexpr int SCALE_I=2944, SHIFT_I=3456, SCALE_O=3968, SHIFT_O=4224;
constexpr int STATS_TOTAL=4480;

__device__ __forceinline__ float lrelu(float v){ return v >= 0.f ? v : SLOPE_*v; }
__device__ __forceinline__ float wave_sum(float v){
  #pragma unroll
  for (int o = 32; o > 0; o >>= 1) v += __shfl_down(v, o, 64);
  return v;
}

// ---------------- zero stats ----------------
__global__ void k_zero(float* s){
  for (int i = threadIdx.x; i < STATS_TOTAL; i += 256) s[i] = 0.f;
}

// ---------------- transpose x -> xT [b][n][c] ----------------
__global__ __launch_bounds__(256) void k_xt(const float* __restrict__ x, float* __restrict__ xT){
  __shared__ float t[32][33];
  const int b = blockIdx.z;
  const int c0 = blockIdx.x*32, n0 = blockIdx.y*32;
  const int tx = threadIdx.x & 31, ty = threadIdx.x >> 5;
  #pragma unroll
  for (int s = 0; s < 32; s += 8)
    t[ty+s][tx] = x[((size_t)b*FIN_ + c0+ty+s)*N_ + n0 + tx];
  __syncthreads();
  #pragma unroll
  for (int s = 0; s < 32; s += 8)
    xT[((size_t)b*N_ + n0+ty+s)*FIN_ + c0 + tx] = t[tx][ty+s];
}

// ---------------- sq norms: XLA:CPU AVX-512 minor-dim reduce on transposed operand ----------------
// VF=16 lanes, lane p accumulates d = p, p+16, ..., p+112 (8 sequential FMAs),
// then llvm.vector.reduce.fadd pairwise tree: halves 8,4,2,1.
__global__ __launch_bounds__(256) void k_sq(const float* __restrict__ x, float* __restrict__ sq){
  int id = blockIdx.x*256 + threadIdx.x;      // < B_*N_
  int b = id >> 11, n = id & (N_-1);
  const float* xb = x + (size_t)b*FIN_*N_ + n;
  float part[16];
  #pragma unroll
  for (int p = 0; p < 16; ++p){
    float a = 0.f;
    #pragma unroll
    for (int q = 0; q < 8; ++q){
      float v = xb[(size_t)(p + 16*q)*N_];
      a = __fmaf_rn(v, v, a);
    }
    part[p] = a;
  }
  #pragma unroll
  for (int off = 8; off > 0; off >>= 1){
    #pragma unroll
    for (int l = 0; l < off; ++l)
      part[l] = __fadd_rn(part[l], part[l+off]);
  }
  sq[id] = part[0];
}

// ---------------- kNN: top-10 (excluding self) ----------------
// dot: Eigen gebp = single accumulator per element, ascending k, FMA.
// dist = ((-2*dot) + sq_i) + sq_j, each op fp32-rounded.
// Ties: stable (lower index first) — no exact ties exist (R8/R9).
__global__ __launch_bounds__(256) void k_knn(const float* __restrict__ x, const float* __restrict__ sq,
                                             int* __restrict__ idx){
  __shared__ float xi[FIN_*64];   // [c][ii]
  __shared__ float xj[FIN_*32];   // [c][jj]
  const int b = blockIdx.y, i0 = blockIdx.x*64;
  const float* xb = x + (size_t)b*FIN_*N_;
  for (int t = threadIdx.x; t < FIN_*64; t += 256){
    int c = t >> 6, ii = t & 63;
    xi[t] = xb[(size_t)c*N_ + i0 + ii];
  }
  const int r = threadIdx.x >> 2, q = threadIdx.x & 3;
  const int i = i0 + r;
  const float sqi = sq[b*N_ + i];
  float bd[10]; int bi[10];
  #pragma unroll
  for (int s = 0; s < 10; ++s){ bd[s] = 1e30f; bi[s] = -1; }
  for (int jt = 0; jt < N_/32; ++jt){
    __syncthreads();
    for (int t = threadIdx.x; t < FIN_*32; t += 256){
      int c = t >> 5, jj = t & 31;
      xj[t] = xb[(size_t)c*N_ + jt*32 + jj];
    }
    __syncthreads();
    float acc[8];
    #pragma unroll
    for (int m = 0; m < 8; ++m) acc[m] = 0.f;
    const int jbase = q*8;
    for (int c = 0; c < FIN_; ++c){
      float a = xi[c*64 + r];
      const float* xr = &xj[c*32 + jbase];
      #pragma unroll
      for (int m = 0; m < 8; ++m) acc[m] = __fmaf_rn(a, xr[m], acc[m]);
    }
    #pragma unroll
    for (int m = 0; m < 8; ++m){
      int j = jt*32 + jbase + m;
      float d = __fadd_rn(__fadd_rn(__fmul_rn(-2.f, acc[m]), sqi), sq[b*N_ + j]);
      if (j == i) d = 1e30f;
      if (d < bd[9]){
        bd[9] = d; bi[9] = j;
        #pragma unroll
        for (int s = 9; s > 0; --s){
          if (bd[s] < bd[s-1]){
            float td = bd[s]; bd[s] = bd[s-1]; bd[s-1] = td;
            int ti = bi[s]; bi[s] = bi[s-1]; bi[s-1] = ti;
          }
        }
      }
    }
  }
  __syncthreads();
  float* dbuf = xi;            // reuse
  int*   ibuf = (int*)xj;      // reuse
  #pragma unroll
  for (int s = 0; s < 10; ++s){
    dbuf[(r*4 + q)*10 + s] = bd[s];
    ibuf[(r*4 + q)*10 + s] = bi[s];
  }
  __syncthreads();
  if (threadIdx.x < 64){
    int rr = threadIdx.x;
    int p[4] = {0,0,0,0};
    int* op = idx + ((size_t)b*N_ + i0 + rr)*K_;
    for (int s = 0; s < K_; ++s){
      float dm = 1e38f; int im = 0x7fffffff; int qm = 0;
      #pragma unroll
      for (int qq = 0; qq < 4; ++qq){
        int pq = p[qq];
        float d  = (pq < 10) ? dbuf[(rr*4+qq)*10 + pq] : 1e38f;
        int   jd = (pq < 10) ? ibuf[(rr*4+qq)*10 + pq] : 0x7fffffff;
        bool take = (d < dm) || (d == dm && jd < im);
        if (take){ dm = d; im = jd; qm = qq; }
      }
      p[qm]++;
      op[s] = im;
    }
  }
}

// ---------------- conv_f / conv_x stats ----------------
__global__ __launch_bounds__(256) void k_fx_stats(const float* __restrict__ x, const float* __restrict__ pc,
                                                  const int* __restrict__ idx,
                                                  const float* __restrict__ Wf, const float* __restrict__ Wx,
                                                  float* __restrict__ stats){
  __shared__ float wfT[256*16];
  __shared__ float wxT[6*16];
  for (int t = threadIdx.x; t < 256*16; t += 256){ int c = t >> 4, o = t & 15; wfT[t] = Wf[o*256 + c]; }
  if (threadIdx.x < 96){ int cc = threadIdx.x >> 4, o = threadIdx.x & 15; wxT[cc*16+o] = Wx[o*6+cc]; }
  __syncthreads();
  const int id = blockIdx.x*256 + threadIdx.x;
  const int b = id >> 11, n = id & (N_-1);
  const float* xb = x + (size_t)b*FIN_*N_;
  const float* pb = pc + (size_t)b*3*N_;
  float yc[16];
  #pragma unroll
  for (int o=0;o<16;++o) yc[o]=0.f;
  for (int c=0;c<FIN_;++c){
    float v = xb[(size_t)c*N_ + n];
    #pragma unroll
    for (int o=0;o<16;++o) yc[o] += wfT[c*16+o]*v;
  }
  float p0=pb[n], p1=pb[N_+n], p2=pb[2*N_+n];
  float sf[16], ssf[16], sx[16], ssx[16];
  #pragma unroll
  for (int o=0;o<16;++o){ sf[o]=0.f;ssf[o]=0.f;sx[o]=0.f;ssx[o]=0.f; }
  for (int kk=0;kk<K_;++kk){
    int j = idx[(size_t)id*K_ + kk];
    float y[16];
    #pragma unroll
    for (int o=0;o<16;++o) y[o]=yc[o];
    for (int c=0;c<FIN_;++c){
      float d = xb[(size_t)c*N_ + j] - xb[(size_t)c*N_ + n];
      #pragma unroll
      for (int o=0;o<16;++o) y[o] += wfT[(128+c)*16+o]*d;
    }
    float q0=pb[j]-p0, q1=pb[N_+j]-p1, q2=pb[2*N_+j]-p2;
    #pragma unroll
    for (int o=0;o<16;++o){
      sf[o]+=y[o]; ssf[o]+=y[o]*y[o];
      float v = wxT[0*16+o]*p0 + wxT[1*16+o]*p1 + wxT[2*16+o]*p2
              + wxT[3*16+o]*q0 + wxT[4*16+o]*q1 + wxT[5*16+o]*q2;
      sx[o]+=v; ssx[o]+=v*v;
    }
  }
  #pragma unroll
  for (int o=0;o<16;++o){
    float v;
    v = wave_sum(sf[o]);  if ((threadIdx.x&63)==0) atomicAdd(&stats[SUM_F+o], v);
    v = wave_sum(ssf[o]); if ((threadIdx.x&63)==0) atomicAdd(&stats[SS_F+o], v);
    v = wave_sum(sx[o]);  if ((threadIdx.x&63)==0) atomicAdd(&stats[SUM_X+o], v);
    v = wave_sum(ssx[o]); if ((threadIdx.x&63)==0) atomicAdd(&stats[SS_X+o], v);
  }
}

// ---------------- finalize BN: scale/shift from sums ----------------
__global__ void k_finalize(float* stats, int sumoff, int ssoff, int nch, float cnt_inv,
                           const float* __restrict__ g, const float* __restrict__ bt,
                           int scoff, int shoff){
  int c = threadIdx.x;
  if (c < nch){
    float mean = stats[sumoff+c]*cnt_inv;
    float var  = stats[ssoff+c]*cnt_inv - mean*mean;
    float rstd = rsqrtf(var + EPS_);
    float sc = g[c]*rstd;
    stats[scoff+c] = sc;
    stats[shoff+c] = bt[c] - mean*sc;
  }
}

// ---------------- wprod = lrelu(bn_f)*lrelu(bn_x)  [px][kk][16] ----------------
__global__ __launch_bounds__(256) void k_wprod(const float* __restrict__ x, const float* __restrict__ pc,
                                               const int* __restrict__ idx,
                                               const float* __restrict__ Wf, const float* __restrict__ Wx,
                                               const float* __restrict__ stats, float* __restrict__ wprod){
  __shared__ float wfT[256*16];
  __shared__ float wxT[6*16];
  __shared__ float scf[16], shf[16], scx[16], shx[16];
  for (int t = threadIdx.x; t < 256*16; t += 256){ int c = t >> 4, o = t & 15; wfT[t] = Wf[o*256 + c]; }
  if (threadIdx.x < 96){ int cc = threadIdx.x >> 4, o = threadIdx.x & 15; wxT[cc*16+o] = Wx[o*6+cc]; }
  if (threadIdx.x < 16){
    scf[threadIdx.x]=stats[SCALE_F+threadIdx.x]; shf[threadIdx.x]=stats[SHIFT_F+threadIdx.x];
    scx[threadIdx.x]=stats[SCALE_X+threadIdx.x]; shx[threadIdx.x]=stats[SHIFT_X+threadIdx.x];
  }
  __syncthreads();
  const int id = blockIdx.x*256 + threadIdx.x;
  const int b = id >> 11, n = id & (N_-1);
  const float* xb = x + (size_t)b*FIN_*N_;
  const float* pb = pc + (size_t)b*3*N_;
  float yc[16];
  #pragma unroll
  for (int o=0;o<16;++o) yc[o]=0.f;
  for (int c=0;c<FIN_;++c){
    float v = xb[(size_t)c*N_ + n];
    #pragma unroll
    for (int o=0;o<16;++o) yc[o] += wfT[c*16+o]*v;
  }
  float p0=pb[n], p1=pb[N_+n], p2=pb[2*N_+n];
  for (int kk=0;kk<K_;++kk){
    int j = idx[(size_t)id*K_ + kk];
    float y[16];
    #pragma unroll
    for (int o=0;o<16;++o) y[o]=yc[o];
    for (int c=0;c<FIN_;++c){
      float d = xb[(size_t)c*N_ + j] - xb[(size_t)c*N_ + n];
      #pragma unroll
      for (int o=0;o<16;++o) y[o] += wfT[(128+c)*16+o]*d;
    }
    float q0=pb[j]-p0, q1=pb[N_+j]-p1, q2=pb[2*N_+j]-p2;
    float* wp = wprod + ((size_t)id*K_ + kk)*16;
    #pragma unroll
    for (int o=0;o<16;++o){
      float vx = wxT[0*16+o]*p0 + wxT[1*16+o]*p1 + wxT[2*16+o]*p2
               + wxT[3*16+o]*q0 + wxT[4*16+o]*q1 + wxT[5*16+o]*q2;
      float a = lrelu(y[o]*scf[o]+shf[o]);
      float bb = lrelu(vx*scx[o]+shx[o]);
      wp[o] = a*bb;
    }
  }
}

// ---------------- a1 stats (conv 16->64 over wprod) ----------------
__global__ __launch_bounds__(256) void k_a1_stats(const float* __restrict__ wprod, const float* __restrict__ Wa1,
                                                  float* __restrict__ stats){
  __shared__ float wp[64*16];
  const int oc = threadIdx.x & 63, sub = threadIdx.x >> 6;
  float wa[16];
  #pragma unroll
  for (int j = 0; j < 16; ++j) wa[j] = Wa1[oc*16+j];
  float s = 0.f, ss = 0.f;
  for (int tile = blockIdx.x; tile < 5120; tile += gridDim.x){
    __syncthreads();
    for (int t = threadIdx.x; t < 1024; t += 256) wp[t] = wprod[(size_t)tile*1024 + t];
    __syncthreads();
    for (int p = sub*16; p < sub*16+16; ++p){
      float y = 0.f;
      #pragma unroll
      for (int j = 0; j < 16; ++j) y += wa[j]*wp[p*16+j];
      s += y; ss += y*y;
    }
  }
  atomicAdd(&stats[SUM_A1+oc], s);
  atomicAdd(&stats[SS_A1+oc], ss);
}

// ---------------- a2 stats (wprod -> a1 -> conv 64->256) ----------------
__global__ __launch_bounds__(256) void k_a2_stats(const float* __restrict__ wprod, const float* __restrict__ Wa1,
                                                  const float* __restrict__ Wa2, float* __restrict__ stats){
  __shared__ float wp[64*16];
  __shared__ float a1t[64*64];
  __shared__ float wa1T[16*64];
  __shared__ float sc1[64], sh1[64];
  for (int t=threadIdx.x;t<1024;t+=256){ int j=t&63, jj=t>>6; wa1T[jj*64+j] = Wa1[j*16+jj]; }
  if (threadIdx.x < 64){ sc1[threadIdx.x]=stats[SCALE_A1+threadIdx.x]; sh1[threadIdx.x]=stats[SHIFT_A1+threadIdx.x]; }
  const int oc = threadIdx.x;
  float wa2[64];
  #pragma unroll
  for (int j=0;j<64;++j) wa2[j] = Wa2[oc*64+j];
  float s=0.f, ss=0.f;
  for (int tile = blockIdx.x; tile < 5120; tile += gridDim.x){
    __syncthreads();
    for (int t=threadIdx.x;t<1024;t+=256) wp[t] = wprod[(size_t)tile*1024 + t];
    __syncthreads();
    for (int t=threadIdx.x;t<4096;t+=256){
      int p = t >> 6, j = t & 63;
      float yv=0.f;
      #pragma unroll
      for (int jj=0;jj<16;++jj) yv += wa1T[jj*64+j]*wp[p*16+jj];
      a1t[t] = lrelu(yv*sc1[j]+sh1[j]);
    }
    __syncthreads();
    #pragma unroll 4
    for (int p=0;p<64;++p){
      float yv=0.f;
      #pragma unroll
      for (int j=0;j<64;++j) yv += wa2[j]*a1t[p*64+j];
      s += yv; ss += yv*yv;
    }
  }
  atomicAdd(&stats[SUM_A2+oc], s);
  atomicAdd(&stats[SS_A2+oc], ss);
}

// ---------------- conv_Wi GEMM: y[512 x 163840] = Wi[512x1536] * im2col(gathered); fused i-stats ----------------
__global__ __launch_bounds__(256) void k_convi(const float* __restrict__ xT, const int* __restrict__ idx,
                                               const float* __restrict__ Wi,
                                               __hip_bfloat16* __restrict__ ybuf, float* __restrict__ stats){
  __shared__ float At[32*128];
  __shared__ float Bt[32*128];
  __shared__ int sIdx[27*10];
  const int r0 = blockIdx.x * 128;     // 4 row tiles
  const int c0 = blockIdx.y * 128;     // 1280 col tiles
  const int pxlo = c0/5;
  const int tx = threadIdx.x & 15, ty = threadIdx.x >> 4;
  float acc[8][8];
  #pragma unroll
  for (int i=0;i<8;++i)
    #pragma unroll
    for (int j=0;j<8;++j) acc[i][j]=0.f;

  {
    int npx = (c0+127)/5 - pxlo + 1;
    for (int t = threadIdx.x; t < npx*10; t += 256)
      sIdx[t] = idx[(size_t)pxlo*10 + t];
  }
  const int colB = threadIdx.x & 127;
  const int kB0  = threadIdx.x >> 7;           // 0/1
  const int gc   = c0 + colB;
  const int pxB  = gc / 5;
  const int tB   = gc - pxB*5;
  const int pxl  = pxB - pxlo;
  const size_t selfbase = (size_t)pxB * FIN_;
  const size_t bbase = (size_t)(pxB >> 11) * N_ * FIN_;
  const int rowA = threadIdx.x >> 3;
  const int kqA  = threadIdx.x & 7;

  for (int k0 = 0; k0 < 1536; k0 += 32){
    __syncthreads();
    #pragma unroll
    for (int s = 0; s < 4; ++s){
      int row = rowA + 32*s;
      const float4 v = *(const float4*)&Wi[(size_t)(r0+row)*1536 + k0 + kqA*4];
      At[(kqA*4+0)*128 + row] = v.x;
      At[(kqA*4+1)*128 + row] = v.y;
      At[(kqA*4+2)*128 + row] = v.z;
      At[(kqA*4+3)*128 + row] = v.w;
    }
    #pragma unroll
    for (int s = 0; s < 16; ++s){
      int k = kB0 + 2*s;
      int kidx = k0 + k;
      int cch = kidx / 6;
      int tau = kidx - cch*6;
      float v;
      if (cch < 128){
        v = xT[selfbase + cch];
      } else {
        int cc = cch - 128;
        int j = sIdx[pxl*10 + tau + tB];
        v = xT[bbase + (size_t)j*FIN_ + cc] - xT[selfbase + cc];
      }
      Bt[k*128 + colB] = v;
    }
    __syncthreads();
    #pragma unroll 8
    for (int k = 0; k < 32; ++k){
      float a[8], b[8];
      #pragma unroll
      for (int m=0;m<8;++m) a[m] = At[k*128 + ty*8 + m];
      #pragma unroll
      for (int m=0;m<8;++m) b[m] = Bt[k*128 + tx*8 + m];
      #pragma unroll
      for (int i=0;i<8;++i)
        #pragma unroll
        for (int j=0;j<8;++j) acc[i][j] += a[i]*b[j];
    }
  }
  float s_r[8], ss_r[8];
  #pragma unroll
  for (int i=0;i<8;++i){
    float s=0.f, ss=0.f;
    #pragma unroll
    for (int j=0;j<8;++j){ float v=acc[i][j]; s+=v; ss+=v*v; }
    s_r[i]=s; ss_r[i]=ss;
  }
  #pragma unroll
  for (int i=0;i<8;++i){
    int row = r0 + ty*8 + i;
    #pragma unroll
    for (int j=0;j<8;++j){
      int col = c0 + tx*8 + j;
      int px = col/5; int t = col - px*5;
      ybuf[(size_t)px*2560 + row*5 + t] = __float2bfloat16(acc[i][j]);
    }
  }
  __syncthreads();
  float* red = At;
  red[threadIdx.x] = 0.f;
  __syncthreads();
  #pragma unroll
  for (int i=0;i<8;++i){
    atomicAdd(&red[(ty*8+i)*2+0], s_r[i]);
    atomicAdd(&red[(ty*8+i)*2+1], ss_r[i]);
  }
  __syncthreads();
  if (threadIdx.x < 128){
    atomicAdd(&stats[SUM_I + r0 + threadIdx.x], red[threadIdx.x*2+0]);
    atomicAdd(&stats[SS_I + r0 + threadIdx.x], red[threadIdx.x*2+1]);
  }
}

// ---------------- w-chain + softmax + bn_i + interleave-multiply (in-place on ybuf, bf16) ----------------
__global__ __launch_bounds__(256) void k_wchain(const float* __restrict__ wprod, const float* __restrict__ Wa1,
                                                const float* __restrict__ Wa2, const float* __restrict__ stats,
                                                __hip_bfloat16* __restrict__ ybuf){
  __shared__ float wp[160];
  __shared__ float a1l[640];
  __shared__ float wa1T[16*64];
  __shared__ float sc1[64], sh1[64];
  const size_t px = blockIdx.x;
  if (threadIdx.x < 160) wp[threadIdx.x] = wprod[px*160 + threadIdx.x];
  for (int t = threadIdx.x; t < 1024; t += 256){ int j = t & 63, jj = t >> 6; wa1T[jj*64+j] = Wa1[j*16+jj]; }
  if (threadIdx.x < 64){ sc1[threadIdx.x]=stats[SCALE_A1+threadIdx.x]; sh1[threadIdx.x]=stats[SHIFT_A1+threadIdx.x]; }
  __syncthreads();
  for (int t = threadIdx.x; t < 640; t += 256){
    int kk = t >> 6, j = t & 63;
    float y=0.f;
    #pragma unroll
    for (int jj=0;jj<16;++jj) y += wa1T[jj*64+j]*wp[kk*16+jj];
    a1l[kk*64+j] = lrelu(y*sc1[j]+sh1[j]);
  }
  __syncthreads();
  const int c = threadIdx.x;
  float wa2[64];
  #pragma unroll
  for (int j=0;j<64;++j) wa2[j] = Wa2[c*64+j];
  const float sc2 = stats[SCALE_A2+c], sh2 = stats[SHIFT_A2+c];
  float wt[10];
  #pragma unroll
  for (int kk=0;kk<10;++kk){
    float y=0.f;
    #pragma unroll
    for (int j=0;j<64;++j) y += wa2[j]*a1l[kk*64+j];
    wt[kk] = lrelu(y*sc2+sh2);
  }
  float mx = wt[0];
  #pragma unroll
  for (int kk=1;kk<10;++kk) mx = fmaxf(mx, wt[kk]);
  float sum = 0.f;
  #pragma unroll
  for (int kk=0;kk<10;++kk){ wt[kk] = __expf(wt[kk]-mx); sum += wt[kk]; }
  float inv = 1.f/sum;
  const float sci0 = stats[SCALE_I + 2*c], shi0 = stats[SHIFT_I + 2*c];
  const float sci1 = stats[SCALE_I + 2*c+1], shi1 = stats[SHIFT_I + 2*c+1];
  __hip_bfloat16* yb = ybuf + px*2560 + c*10;
  #pragma unroll
  for (int q = 0; q < 10; ++q){
    float v = __bfloat162float(yb[q]);
    float sc = (q < 5) ? sci0 : sci1;
    float sh = (q < 5) ? shi0 : shi1;
    yb[q] = __float2bfloat16(lrelu(v*sc+sh) * (wt[q]*inv));
  }
}

// ---------------- permute W2 to k-order (efea rows then inte rows) ----------------
__global__ __launch_bounds__(256) void k_permw2(const float* __restrict__ W2, float* __restrict__ W2p){
  const unsigned total = 256u*5120u;
  for (unsigned e = blockIdx.x*256u + threadIdx.x; e < total; e += gridDim.x*256u){
    unsigned oc = e / 5120u; unsigned k = e - oc*5120u;
    unsigned half = (k >= 2560u) ? 1u : 0u;
    unsigned kk2 = k - half*2560u;
    unsigned cch = kk2 / 10u, w = kk2 - cch*10u + half*10u;
    W2p[e] = W2[(size_t)oc*5120u + cch*20u + w];
  }
}

// ---------------- W2 GEMM: out_pre[256 x 32768]; e_fea half gathered, inte half from bf16; fused o-stats ----------------
__global__ __launch_bounds__(256) void k_w2(const float* __restrict__ xT, const int* __restrict__ idx,
                                            const __hip_bfloat16* __restrict__ inte,
                                            const float* __restrict__ W2p, float* __restrict__ outpre,
                                            float* __restrict__ stats){
  __shared__ float At[32*128];
  __shared__ float Bt[32*128];
  __shared__ int sIdx[128*10];
  const int r0 = blockIdx.x * 128;   // 2 row tiles
  const int c0 = blockIdx.y * 128;   // 256 col tiles (cols = px)
  for (int t = threadIdx.x; t < 1280; t += 256) sIdx[t] = idx[(size_t)c0*10 + t];
  const int tx = threadIdx.x & 15, ty = threadIdx.x >> 4;
  float acc[8][8];
  #pragma unroll
  for (int i=0;i<8;++i)
    #pragma unroll
    for (int j=0;j<8;++j) acc[i][j]=0.f;
  const int rowA = threadIdx.x >> 3;
  const int kqA  = threadIdx.x & 7;
  const int colB = threadIdx.x & 127;
  const int kB0  = threadIdx.x >> 7;
  const int pxg  = c0 + colB;
  const size_t selfbase = (size_t)pxg * FIN_;
  const size_t bbase = (size_t)(pxg >> 11) * N_ * FIN_;
  const __hip_bfloat16* ib = inte + (size_t)pxg*2560;

  for (int k0 = 0; k0 < 5120; k0 += 32){
    __syncthreads();
    #pragma unroll
    for (int s = 0; s < 4; ++s){
      int row = rowA + 32*s;
      const float4 v = *(const float4*)&W2p[(size_t)(r0+row)*5120 + k0 + kqA*4];
      At[(kqA*4+0)*128+row]=v.x; At[(kqA*4+1)*128+row]=v.y;
      At[(kqA*4+2)*128+row]=v.z; At[(kqA*4+3)*128+row]=v.w;
    }
    #pragma unroll
    for (int s = 0; s < 16; ++s){
      int k = kB0 + 2*s;
      int kidx = k0 + k;
      float v;
      if (kidx < 2560){
        int c = kidx / 10, w = kidx - c*10;
        if (c < 128) v = xT[selfbase + c];
        else {
          int j = sIdx[colB*10 + w];
          v = xT[bbase + (size_t)j*FIN_ + (c-128)] - xT[selfbase + (c-128)];
        }
      } else {
        v = __bfloat162float(ib[kidx - 2560]);
      }
      Bt[k*128 + colB] = v;
    }
    __syncthreads();
    #pragma unroll 8
    for (int k = 0; k < 32; ++k){
      float a[8], b[8];
      #pragma unroll
      for (int m=0;m<8;++m) a[m] = At[k*128 + ty*8 + m];
      #pragma unroll
      for (int m=0;m<8;++m) b[m] = Bt[k*128 + tx*8 + m];
      #pragma unroll
      for (int i=0;i<8;++i)
        #pragma unroll
        for (int j=0;j<8;++j) acc[i][j] += a[i]*b[j];
    }
  }
  float s_r[8], ss_r[8];
  #pragma unroll
  for (int i=0;i<8;++i){
    float s=0.f, ss=0.f;
    #pragma unroll
    for (int j=0;j<8;++j){ float v=acc[i][j]; s+=v; ss+=v*v; }
    s_r[i]=s; ss_r[i]=ss;
  }
  #pragma unroll
  for (int i=0;i<8;++i){
    size_t row = (size_t)(r0 + ty*8 + i);
    #pragma unroll
    for (int j=0;j<8;++j){
      outpre[row*32768 + c0 + tx*8 + j] = acc[i][j];
    }
  }
  __syncthreads();
  float* red = At;
  red[threadIdx.x] = 0.f;
  __syncthreads();
  #pragma unroll
  for (int i=0;i<8;++i){
    atomicAdd(&red[(ty*8+i)*2+0], s_r[i]);
    atomicAdd(&red[(ty*8+i)*2+1], ss_r[i]);
  }
  __syncthreads();
  if (threadIdx.x < 128){
    atomicAdd(&stats[SUM_O + r0 + threadIdx.x], red[threadIdx.x*2+0]);
    atomicAdd(&stats[SS_O + r0 + threadIdx.x], red[threadIdx.x*2+1]);
  }
}

// ---------------- final: bn2 + relu + reshape to [B,128,4096] ----------------
__global__ __launch_bounds__(256) void k_final(const float* __restrict__ outpre, const float* __restrict__ stats,
                                               float* __restrict__ out){
  const unsigned total = (unsigned)B_*128u*4096u;
  for (unsigned e = blockIdx.x*256u + threadIdx.x; e < total; e += gridDim.x*256u){
    unsigned b = e >> 19;
    unsigned rem = e & ((1u<<19)-1u);
    unsigned f = rem >> 12;
    unsigned m = rem & 4095u;
    unsigned half = m >> 11;
    unsigned n = m & 2047u;
    unsigned c = f*2u + half;
    float pre = outpre[(size_t)c*32768 + b*2048 + n];
    float v = pre*stats[SCALE_O+c] + stats[SHIFT_O+c];
    out[e] = fmaxf(v, 0.f);
  }
}

extern "C" void kernel_launch(void* const* d_in, const int* in_sizes, int n_in,
                              void* d_out, int out_size, void* d_ws, size_t ws_size,
                              hipStream_t stream) {
  (void)in_sizes; (void)n_in; (void)out_size;
  const float* x    = (const float*)d_in[0];
  const float* pc   = (const float*)d_in[1];
  const float* Wf   = (const float*)d_in[2];
  const float* gf   = (const float*)d_in[4];
  const float* btf  = (const float*)d_in[5];
  const float* Wx   = (const float*)d_in[6];
  const float* gx   = (const float*)d_in[8];
  const float* btx  = (const float*)d_in[9];
  const float* Wa1  = (const float*)d_in[10];
  const float* ga1  = (const float*)d_in[12];
  const float* bta1 = (const float*)d_in[13];
  const float* Wa2  = (const float*)d_in[14];
  const float* ga2  = (const float*)d_in[16];
  const float* bta2 = (const float*)d_in[17];
  const float* Wi   = (const float*)d_in[18];
  const float* gi   = (const float*)d_in[20];
  const float* bti  = (const float*)d_in[21];
  const float* W2   = (const float*)d_in[22];
  const float* g2   = (const float*)d_in[24];
  const float* bt2  = (const float*)d_in[25];
  float* out = (float*)d_out;

  char* ws = (char*)d_ws;
  float*  stats  = (float*)ws;                          //        0 ..    32768
  int*    idx    = (int*)  (ws + 32768);                //    32768 ..  1343488
  float*  sq     = (float*)(ws + 1343488);              //  1343488 ..  1605632 (uses first 131072)
  float*  wprod  = (float*)(ws + 1605632);              //  1605632 .. 22577152
  float*  xT     = (float*)(ws + 22577152);             // 22577152 .. 39354368
  float*  W2p    = (float*)(ws + 39354368);             // 39354368 .. 44597248
  float*  outpre = (float*)(ws + 44597248);             // 44597248 .. 78151680
  __hip_bfloat16* ybuf = (__hip_bfloat16*)(ws + 78151680); // 78151680 .. 245923840
  if (ws_size < 245923840ULL) {
    fprintf(stderr, "kernel_launch: ws_size %zu < required 245923840\n", ws_size);
    return;
  }

  k_zero<<<1, 256, 0, stream>>>(stats);
  k_xt<<<dim3(FIN_/32, N_/32, B_), 256, 0, stream>>>(x, xT);
  k_sq<<<(B_*N_)/256, 256, 0, stream>>>(x, sq);
  k_knn<<<dim3(N_/64, B_), 256, 0, stream>>>(x, sq, idx);
  k_permw2<<<2048, 256, 0, stream>>>(W2, W2p);

  k_fx_stats<<<(B_*N_)/256, 256, 0, stream>>>(x, pc, idx, Wf, Wx, stats);
  k_finalize<<<1, 512, 0, stream>>>(stats, SUM_F, SS_F, 16, 1.f/327680.f, gf, btf, SCALE_F, SHIFT_F);
  k_finalize<<<1, 512, 0, stream>>>(stats, SUM_X, SS_X, 16, 1.f/327680.f, gx, btx, SCALE_X, SHIFT_X);

  k_wprod<<<(B_*N_)/256, 256, 0, stream>>>(x, pc, idx, Wf, Wx, stats, wprod);
  k_a1_stats<<<512, 256, 0, stream>>>(wprod, Wa1, stats);
  k_finalize<<<1, 512, 0, stream>>>(stats, SUM_A1, SS_A1, 64, 1.f/327680.f, ga1, bta1, SCALE_A1, SHIFT_A1);

  k_a2_stats<<<512, 256, 0, stream>>>(wprod, Wa1, Wa2, stats);
  k_finalize<<<1, 512, 0, stream>>>(stats, SUM_A2, SS_A2, 256, 1.f/327680.f, ga2, bta2, SCALE_A2, SHIFT_A2);

  k_convi<<<dim3(4, 1280), 256, 0, stream>>>(xT, idx, Wi, ybuf, stats);
  k_finalize<<<1, 512, 0, stream>>>(stats, SUM_I, SS_I, 512, 1.f/163840.f, gi, bti, SCALE_I, SHIFT_I);

  k_wchain<<<B_*N_, 256, 0, stream>>>(wprod, Wa1, Wa2, stats, ybuf);

  k_w2<<<dim3(2, 256), 256, 0, stream>>>(xT, idx, ybuf, W2p, outpre, stats);
  k_finalize<<<1, 512, 0, stream>>>(stats, SUM_O, SS_O, 256, 1.f/32768.f, g2, bt2, SCALE_O, SHIFT_O);

  k_final<<<4096, 256, 0, stream>>>(outpre, stats, out);
}

// Round 15
// 6515.986 us; speedup vs baseline: 1.2392x; 1.2392x over previous
//
#include <hip/hip_runtime.h>
#include <hip/hip_bf16.h>
#include <cstdio>
#include <cstddef>

#define B_    16
#define FIN_  128
#define N_    2048
#define K_    10
#define EPS_  1e-5f
#define SLOPE_ 0.01f

typedef float f32x4 __attribute__((ext_vector_type(4)));
typedef short s16x8 __attribute__((ext_vector_type(8)));

// ---- stats region layout (floats) ----
constexpr int SUM_F=0,   SS_F=16,   SUM_X=32,  SS_X=48;
constexpr int SUM_A1=64, SS_A1=128, SUM_A2=192,SS_A2=448;
constexpr int SUM_I=704, SS_I=1216, SUM_O=1728,SS_O=1984;
constexpr int SCALE_F=2240, SHIFT_F=2256, SCALE_X=2272, SHIFT_X=2288;
constexpr int SCALE_A1=2304, SHIFT_A1=2368, SCALE_A2=2432, SHIFT_A2=2688;
constexpr int SCALE_I=2944, SHIFT_I=3456, SCALE_O=3968, SHIFT_O=4224;
constexpr int STATS_TOTAL=4480;

__device__ __forceinline__ float lrelu(float v){ return v >= 0.f ? v : SLOPE_*v; }
__device__ __forceinline__ float wave_sum(float v){
  #pragma unroll
  for (int o = 32; o > 0; o >>= 1) v += __shfl_down(v, o, 64);
  return v;
}
__device__ __forceinline__ unsigned short f2bf(float f){
  __hip_bfloat16 h = __float2bfloat16(f);
  return *reinterpret_cast<unsigned short*>(&h);
}

// ---------------- zero stats ----------------
__global__ void k_zero(float* s){
  for (int i = threadIdx.x; i < STATS_TOTAL; i += 256) s[i] = 0.f;
}

// ---------------- transpose x -> xT [b][n][c] ----------------
__global__ __launch_bounds__(256) void k_xt(const float* __restrict__ x, float* __restrict__ xT){
  __shared__ float t[32][33];
  const int b = blockIdx.z;
  const int c0 = blockIdx.x*32, n0 = blockIdx.y*32;
  const int tx = threadIdx.x & 31, ty = threadIdx.x >> 5;
  #pragma unroll
  for (int s = 0; s < 32; s += 8)
    t[ty+s][tx] = x[((size_t)b*FIN_ + c0+ty+s)*N_ + n0 + tx];
  __syncthreads();
  #pragma unroll
  for (int s = 0; s < 32; s += 8)
    xT[((size_t)b*N_ + n0+ty+s)*FIN_ + c0 + tx] = t[tx][ty+s];
}

// ---------------- sq norms: XLA:CPU AVX-512 minor-dim reduce (MATCHED — do not change) ----------------
__global__ __launch_bounds__(256) void k_sq(const float* __restrict__ x, float* __restrict__ sq){
  int id = blockIdx.x*256 + threadIdx.x;      // < B_*N_
  int b = id >> 11, n = id & (N_-1);
  const float* xb = x + (size_t)b*FIN_*N_ + n;
  float part[16];
  #pragma unroll
  for (int p = 0; p < 16; ++p){
    float a = 0.f;
    #pragma unroll
    for (int q = 0; q < 8; ++q){
      float v = xb[(size_t)(p + 16*q)*N_];
      a = __fmaf_rn(v, v, a);
    }
    part[p] = a;
  }
  #pragma unroll
  for (int off = 8; off > 0; off >>= 1){
    #pragma unroll
    for (int l = 0; l < off; ++l)
      part[l] = __fadd_rn(part[l], part[l+off]);
  }
  sq[id] = part[0];
}

// ---------------- kNN: top-10 (excluding self) (MATCHED — do not change) ----------------
__global__ __launch_bounds__(256) void k_knn(const float* __restrict__ x, const float* __restrict__ sq,
                                             int* __restrict__ idx){
  __shared__ float xi[FIN_*64];   // [c][ii]
  __shared__ float xj[FIN_*32];   // [c][jj]
  const int b = blockIdx.y, i0 = blockIdx.x*64;
  const float* xb = x + (size_t)b*FIN_*N_;
  for (int t = threadIdx.x; t < FIN_*64; t += 256){
    int c = t >> 6, ii = t & 63;
    xi[t] = xb[(size_t)c*N_ + i0 + ii];
  }
  const int r = threadIdx.x >> 2, q = threadIdx.x & 3;
  const int i = i0 + r;
  const float sqi = sq[b*N_ + i];
  float bd[10]; int bi[10];
  #pragma unroll
  for (int s = 0; s < 10; ++s){ bd[s] = 1e30f; bi[s] = -1; }
  for (int jt = 0; jt < N_/32; ++jt){
    __syncthreads();
    for (int t = threadIdx.x; t < FIN_*32; t += 256){
      int c = t >> 5, jj = t & 31;
      xj[t] = xb[(size_t)c*N_ + jt*32 + jj];
    }
    __syncthreads();
    float acc[8];
    #pragma unroll
    for (int m = 0; m < 8; ++m) acc[m] = 0.f;
    const int jbase = q*8;
    for (int c = 0; c < FIN_; ++c){
      float a = xi[c*64 + r];
      const float* xr = &xj[c*32 + jbase];
      #pragma unroll
      for (int m = 0; m < 8; ++m) acc[m] = __fmaf_rn(a, xr[m], acc[m]);
    }
    #pragma unroll
    for (int m = 0; m < 8; ++m){
      int j = jt*32 + jbase + m;
      float d = __fadd_rn(__fadd_rn(__fmul_rn(-2.f, acc[m]), sqi), sq[b*N_ + j]);
      if (j == i) d = 1e30f;
      if (d < bd[9]){
        bd[9] = d; bi[9] = j;
        #pragma unroll
        for (int s = 9; s > 0; --s){
          if (bd[s] < bd[s-1]){
            float td = bd[s]; bd[s] = bd[s-1]; bd[s-1] = td;
            int ti = bi[s]; bi[s] = bi[s-1]; bi[s-1] = ti;
          }
        }
      }
    }
  }
  __syncthreads();
  float* dbuf = xi;            // reuse
  int*   ibuf = (int*)xj;      // reuse
  #pragma unroll
  for (int s = 0; s < 10; ++s){
    dbuf[(r*4 + q)*10 + s] = bd[s];
    ibuf[(r*4 + q)*10 + s] = bi[s];
  }
  __syncthreads();
  if (threadIdx.x < 64){
    int rr = threadIdx.x;
    int p[4] = {0,0,0,0};
    int* op = idx + ((size_t)b*N_ + i0 + rr)*K_;
    for (int s = 0; s < K_; ++s){
      float dm = 1e38f; int im = 0x7fffffff; int qm = 0;
      #pragma unroll
      for (int qq = 0; qq < 4; ++qq){
        int pq = p[qq];
        float d  = (pq < 10) ? dbuf[(rr*4+qq)*10 + pq] : 1e38f;
        int   jd = (pq < 10) ? ibuf[(rr*4+qq)*10 + pq] : 0x7fffffff;
        bool take = (d < dm) || (d == dm && jd < im);
        if (take){ dm = d; im = jd; qm = qq; }
      }
      p[qm]++;
      op[s] = im;
    }
  }
}

// ---------------- conv_f / conv_x stats ----------------
__global__ __launch_bounds__(256) void k_fx_stats(const float* __restrict__ x, const float* __restrict__ pc,
                                                  const int* __restrict__ idx,
                                                  const float* __restrict__ Wf, const float* __restrict__ Wx,
                                                  float* __restrict__ stats){
  __shared__ float wfT[256*16];
  __shared__ float wxT[6*16];
  for (int t = threadIdx.x; t < 256*16; t += 256){ int c = t >> 4, o = t & 15; wfT[t] = Wf[o*256 + c]; }
  if (threadIdx.x < 96){ int cc = threadIdx.x >> 4, o = threadIdx.x & 15; wxT[cc*16+o] = Wx[o*6+cc]; }
  __syncthreads();
  const int id = blockIdx.x*256 + threadIdx.x;
  const int b = id >> 11, n = id & (N_-1);
  const float* xb = x + (size_t)b*FIN_*N_;
  const float* pb = pc + (size_t)b*3*N_;
  float yc[16];
  #pragma unroll
  for (int o=0;o<16;++o) yc[o]=0.f;
  for (int c=0;c<FIN_;++c){
    float v = xb[(size_t)c*N_ + n];
    #pragma unroll
    for (int o=0;o<16;++o) yc[o] += wfT[c*16+o]*v;
  }
  float p0=pb[n], p1=pb[N_+n], p2=pb[2*N_+n];
  float sf[16], ssf[16], sx[16], ssx[16];
  #pragma unroll
  for (int o=0;o<16;++o){ sf[o]=0.f;ssf[o]=0.f;sx[o]=0.f;ssx[o]=0.f; }
  for (int kk=0;kk<K_;++kk){
    int j = idx[(size_t)id*K_ + kk];
    float y[16];
    #pragma unroll
    for (int o=0;o<16;++o) y[o]=yc[o];
    for (int c=0;c<FIN_;++c){
      float d = xb[(size_t)c*N_ + j] - xb[(size_t)c*N_ + n];
      #pragma unroll
      for (int o=0;o<16;++o) y[o] += wfT[(128+c)*16+o]*d;
    }
    float q0=pb[j]-p0, q1=pb[N_+j]-p1, q2=pb[2*N_+j]-p2;
    #pragma unroll
    for (int o=0;o<16;++o){
      sf[o]+=y[o]; ssf[o]+=y[o]*y[o];
      float v = wxT[0*16+o]*p0 + wxT[1*16+o]*p1 + wxT[2*16+o]*p2
              + wxT[3*16+o]*q0 + wxT[4*16+o]*q1 + wxT[5*16+o]*q2;
      sx[o]+=v; ssx[o]+=v*v;
    }
  }
  #pragma unroll
  for (int o=0;o<16;++o){
    float v;
    v = wave_sum(sf[o]);  if ((threadIdx.x&63)==0) atomicAdd(&stats[SUM_F+o], v);
    v = wave_sum(ssf[o]); if ((threadIdx.x&63)==0) atomicAdd(&stats[SS_F+o], v);
    v = wave_sum(sx[o]);  if ((threadIdx.x&63)==0) atomicAdd(&stats[SUM_X+o], v);
    v = wave_sum(ssx[o]); if ((threadIdx.x&63)==0) atomicAdd(&stats[SS_X+o], v);
  }
}

// ---------------- finalize BN: scale/shift from sums ----------------
__global__ void k_finalize(float* stats, int sumoff, int ssoff, int nch, float cnt_inv,
                           const float* __restrict__ g, const float* __restrict__ bt,
                           int scoff, int shoff){
  int c = threadIdx.x;
  if (c < nch){
    float mean = stats[sumoff+c]*cnt_inv;
    float var  = stats[ssoff+c]*cnt_inv - mean*mean;
    float rstd = rsqrtf(var + EPS_);
    float sc = g[c]*rstd;
    stats[scoff+c] = sc;
    stats[shoff+c] = bt[c] - mean*sc;
  }
}

// ---------------- wprod = lrelu(bn_f)*lrelu(bn_x)  [px][kk][16] ----------------
__global__ __launch_bounds__(256) void k_wprod(const float* __restrict__ x, const float* __restrict__ pc,
                                               const int* __restrict__ idx,
                                               const float* __restrict__ Wf, const float* __restrict__ Wx,
                                               const float* __restrict__ stats, float* __restrict__ wprod){
  __shared__ float wfT[256*16];
  __shared__ float wxT[6*16];
  __shared__ float scf[16], shf[16], scx[16], shx[16];
  for (int t = threadIdx.x; t < 256*16; t += 256){ int c = t >> 4, o = t & 15; wfT[t] = Wf[o*256 + c]; }
  if (threadIdx.x < 96){ int cc = threadIdx.x >> 4, o = threadIdx.x & 15; wxT[cc*16+o] = Wx[o*6+cc]; }
  if (threadIdx.x < 16){
    scf[threadIdx.x]=stats[SCALE_F+threadIdx.x]; shf[threadIdx.x]=stats[SHIFT_F+threadIdx.x];
    scx[threadIdx.x]=stats[SCALE_X+threadIdx.x]; shx[threadIdx.x]=stats[SHIFT_X+threadIdx.x];
  }
  __syncthreads();
  const int id = blockIdx.x*256 + threadIdx.x;
  const int b = id >> 11, n = id & (N_-1);
  const float* xb = x + (size_t)b*FIN_*N_;
  const float* pb = pc + (size_t)b*3*N_;
  float yc[16];
  #pragma unroll
  for (int o=0;o<16;++o) yc[o]=0.f;
  for (int c=0;c<FIN_;++c){
    float v = xb[(size_t)c*N_ + n];
    #pragma unroll
    for (int o=0;o<16;++o) yc[o] += wfT[c*16+o]*v;
  }
  float p0=pb[n], p1=pb[N_+n], p2=pb[2*N_+n];
  for (int kk=0;kk<K_;++kk){
    int j = idx[(size_t)id*K_ + kk];
    float y[16];
    #pragma unroll
    for (int o=0;o<16;++o) y[o]=yc[o];
    for (int c=0;c<FIN_;++c){
      float d = xb[(size_t)c*N_ + j] - xb[(size_t)c*N_ + n];
      #pragma unroll
      for (int o=0;o<16;++o) y[o] += wfT[(128+c)*16+o]*d;
    }
    float q0=pb[j]-p0, q1=pb[N_+j]-p1, q2=pb[2*N_+j]-p2;
    float* wp = wprod + ((size_t)id*K_ + kk)*16;
    #pragma unroll
    for (int o=0;o<16;++o){
      float vx = wxT[0*16+o]*p0 + wxT[1*16+o]*p1 + wxT[2*16+o]*p2
               + wxT[3*16+o]*q0 + wxT[4*16+o]*q1 + wxT[5*16+o]*q2;
      float a = lrelu(y[o]*scf[o]+shf[o]);
      float bb = lrelu(vx*scx[o]+shx[o]);
      wp[o] = a*bb;
    }
  }
}

// ---------------- a1 stats (conv 16->64 over wprod) ----------------
__global__ __launch_bounds__(256) void k_a1_stats(const float* __restrict__ wprod, const float* __restrict__ Wa1,
                                                  float* __restrict__ stats){
  __shared__ float wp[64*16];
  const int oc = threadIdx.x & 63, sub = threadIdx.x >> 6;
  float wa[16];
  #pragma unroll
  for (int j = 0; j < 16; ++j) wa[j] = Wa1[oc*16+j];
  float s = 0.f, ss = 0.f;
  for (int tile = blockIdx.x; tile < 5120; tile += gridDim.x){
    __syncthreads();
    for (int t = threadIdx.x; t < 1024; t += 256) wp[t] = wprod[(size_t)tile*1024 + t];
    __syncthreads();
    for (int p = sub*16; p < sub*16+16; ++p){
      float y = 0.f;
      #pragma unroll
      for (int j = 0; j < 16; ++j) y += wa[j]*wp[p*16+j];
      s += y; ss += y*y;
    }
  }
  atomicAdd(&stats[SUM_A1+oc], s);
  atomicAdd(&stats[SS_A1+oc], ss);
}

// ---------------- a2 stats (wprod -> a1 -> conv 64->256) ----------------
__global__ __launch_bounds__(256) void k_a2_stats(const float* __restrict__ wprod, const float* __restrict__ Wa1,
                                                  const float* __restrict__ Wa2, float* __restrict__ stats){
  __shared__ float wp[64*16];
  __shared__ float a1t[64*64];
  __shared__ float wa1T[16*64];
  __shared__ float sc1[64], sh1[64];
  for (int t=threadIdx.x;t<1024;t+=256){ int j=t&63, jj=t>>6; wa1T[jj*64+j] = Wa1[j*16+jj]; }
  if (threadIdx.x < 64){ sc1[threadIdx.x]=stats[SCALE_A1+threadIdx.x]; sh1[threadIdx.x]=stats[SHIFT_A1+threadIdx.x]; }
  const int oc = threadIdx.x;
  float wa2[64];
  #pragma unroll
  for (int j=0;j<64;++j) wa2[j] = Wa2[oc*64+j];
  float s=0.f, ss=0.f;
  for (int tile = blockIdx.x; tile < 5120; tile += gridDim.x){
    __syncthreads();
    for (int t=threadIdx.x;t<1024;t+=256) wp[t] = wprod[(size_t)tile*1024 + t];
    __syncthreads();
    for (int t=threadIdx.x;t<4096;t+=256){
      int p = t >> 6, j = t & 63;
      float yv=0.f;
      #pragma unroll
      for (int jj=0;jj<16;++jj) yv += wa1T[jj*64+j]*wp[p*16+jj];
      a1t[t] = lrelu(yv*sc1[j]+sh1[j]);
    }
    __syncthreads();
    #pragma unroll 4
    for (int p=0;p<64;++p){
      float yv=0.f;
      #pragma unroll
      for (int j=0;j<64;++j) yv += wa2[j]*a1t[p*64+j];
      s += yv; ss += yv*yv;
    }
  }
  atomicAdd(&stats[SUM_A2+oc], s);
  atomicAdd(&stats[SS_A2+oc], ss);
}

// ---------------- conv_Wi GEMM (bf16 MFMA): y[512 x 163840] = Wi * im2col(gathered); fused i-stats ----------------
// 128x128 C-tile per block; 4 waves, each 64x64 via 4x4 MFMA(16x16x32) accs.
// LDS: As[row][k] bf16 stride 40 (16B-aligned b128 frags, <=2-way banks), Bs[col][k] same.
__global__ __launch_bounds__(256) void k_convi(const float* __restrict__ xT, const int* __restrict__ idx,
                                               const float* __restrict__ Wi,
                                               __hip_bfloat16* __restrict__ ybuf, float* __restrict__ stats){
  __shared__ __align__(16) unsigned short As[128*40];
  __shared__ __align__(16) unsigned short Bs[128*40];
  __shared__ int sIdx[27*10];
  const int r0 = blockIdx.x * 128;     // 4 row tiles
  const int c0 = blockIdx.y * 128;     // 1280 col tiles
  const int pxlo = c0/5;
  {
    int npx = (c0+127)/5 - pxlo + 1;
    for (int t = threadIdx.x; t < npx*10; t += 256)
      sIdx[t] = idx[(size_t)pxlo*10 + t];
  }
  // staging roles
  const int rowA  = threadIdx.x >> 1;          // 0..127
  const int halfA = threadIdx.x & 1;           // 0/1 -> k offset 0/16
  const float* wrow = &Wi[(size_t)(r0+rowA)*1536 + halfA*16];
  const int colJ = threadIdx.x >> 1;           // 0..127
  const int ksJ  = (threadIdx.x & 1)*16;
  const int gcJ  = c0 + colJ;
  const int pxJ  = gcJ/5;
  const int tJ   = gcJ - pxJ*5;
  const int pxlJ = pxJ - pxlo;
  const size_t selfJ  = (size_t)pxJ*FIN_;
  const size_t bbaseJ = (size_t)(pxJ >> 11)*N_*FIN_;
  // MFMA roles
  const int wave = threadIdx.x >> 6, lane = threadIdx.x & 63;
  const int quad = lane >> 4, l16 = lane & 15;
  const int wm = wave & 1, wn = wave >> 1;

  f32x4 acc[4][4] = {};

  for (int k0 = 0; k0 < 1536; k0 += 32){
    __syncthreads();
    // stage A: Wi[128 x 32] -> bf16
    {
      const float4 v0 = *(const float4*)&wrow[k0+0];
      const float4 v1 = *(const float4*)&wrow[k0+4];
      const float4 v2 = *(const float4*)&wrow[k0+8];
      const float4 v3 = *(const float4*)&wrow[k0+12];
      unsigned short* dst = &As[rowA*40 + halfA*16];
      dst[0]=f2bf(v0.x); dst[1]=f2bf(v0.y); dst[2]=f2bf(v0.z); dst[3]=f2bf(v0.w);
      dst[4]=f2bf(v1.x); dst[5]=f2bf(v1.y); dst[6]=f2bf(v1.z); dst[7]=f2bf(v1.w);
      dst[8]=f2bf(v2.x); dst[9]=f2bf(v2.y); dst[10]=f2bf(v2.z); dst[11]=f2bf(v2.w);
      dst[12]=f2bf(v3.x); dst[13]=f2bf(v3.y); dst[14]=f2bf(v3.z); dst[15]=f2bf(v3.w);
    }
    // stage B: im2col gather [128 cols x 32 k] -> bf16 (layout [col][k])
    {
      unsigned short* bdst = &Bs[colJ*40 + ksJ];
      #pragma unroll
      for (int kk = 0; kk < 16; ++kk){
        int kidx = k0 + ksJ + kk;
        int cch = kidx / 6;
        int tau = kidx - cch*6;
        float v;
        if (cch < 128){
          v = xT[selfJ + cch];
        } else {
          int cc = cch - 128;
          int j = sIdx[pxlJ*10 + tau + tJ];
          v = xT[bbaseJ + (size_t)j*FIN_ + cc] - xT[selfJ + cc];
        }
        bdst[kk] = f2bf(v);
      }
    }
    __syncthreads();
    s16x8 af[4], bfr[4];
    #pragma unroll
    for (int mt = 0; mt < 4; ++mt)
      af[mt] = *(const s16x8*)&As[(wm*64 + mt*16 + l16)*40 + quad*8];
    #pragma unroll
    for (int nt = 0; nt < 4; ++nt)
      bfr[nt] = *(const s16x8*)&Bs[(wn*64 + nt*16 + l16)*40 + quad*8];
    #pragma unroll
    for (int mt = 0; mt < 4; ++mt)
      #pragma unroll
      for (int nt = 0; nt < 4; ++nt)
        acc[mt][nt] = __builtin_amdgcn_mfma_f32_16x16x32_bf16(af[mt], bfr[nt], acc[mt][nt], 0, 0, 0);
  }

  // epilogue: fused i-stats + interleaved bf16 C write
  __syncthreads();
  float* red = (float*)As;   // reuse (256 floats)
  red[threadIdx.x] = 0.f;
  __syncthreads();
  #pragma unroll
  for (int mt = 0; mt < 4; ++mt){
    const int rowLbase = wm*64 + mt*16 + quad*4;
    #pragma unroll
    for (int reg = 0; reg < 4; ++reg){
      float s = 0.f, ss = 0.f;
      #pragma unroll
      for (int nt = 0; nt < 4; ++nt){ float v = acc[mt][nt][reg]; s += v; ss += v*v; }
      atomicAdd(&red[(rowLbase+reg)*2+0], s);
      atomicAdd(&red[(rowLbase+reg)*2+1], ss);
    }
  }
  #pragma unroll
  for (int mt = 0; mt < 4; ++mt){
    #pragma unroll
    for (int nt = 0; nt < 4; ++nt){
      const int col = c0 + wn*64 + nt*16 + l16;
      const int px = col/5, t5 = col - px*5;
      #pragma unroll
      for (int reg = 0; reg < 4; ++reg){
        const int row = r0 + wm*64 + mt*16 + quad*4 + reg;
        ybuf[(size_t)px*2560 + row*5 + t5] = __float2bfloat16(acc[mt][nt][reg]);
      }
    }
  }
  __syncthreads();
  if (threadIdx.x < 128){
    atomicAdd(&stats[SUM_I + r0 + threadIdx.x], red[threadIdx.x*2+0]);
    atomicAdd(&stats[SS_I + r0 + threadIdx.x], red[threadIdx.x*2+1]);
  }
}

// ---------------- w-chain + softmax + bn_i + interleave-multiply (in-place on ybuf, bf16) ----------------
__global__ __launch_bounds__(256) void k_wchain(const float* __restrict__ wprod, const float* __restrict__ Wa1,
                                                const float* __restrict__ Wa2, const float* __restrict__ stats,
                                                __hip_bfloat16* __restrict__ ybuf){
  __shared__ float wp[160];
  __shared__ float a1l[640];
  __shared__ float wa1T[16*64];
  __shared__ float sc1[64], sh1[64];
  const size_t px = blockIdx.x;
  if (threadIdx.x < 160) wp[threadIdx.x] = wprod[px*160 + threadIdx.x];
  for (int t = threadIdx.x; t < 1024; t += 256){ int j = t & 63, jj = t >> 6; wa1T[jj*64+j] = Wa1[j*16+jj]; }
  if (threadIdx.x < 64){ sc1[threadIdx.x]=stats[SCALE_A1+threadIdx.x]; sh1[threadIdx.x]=stats[SHIFT_A1+threadIdx.x]; }
  __syncthreads();
  for (int t = threadIdx.x; t < 640; t += 256){
    int kk = t >> 6, j = t & 63;
    float y=0.f;
    #pragma unroll
    for (int jj=0;jj<16;++jj) y += wa1T[jj*64+j]*wp[kk*16+jj];
    a1l[kk*64+j] = lrelu(y*sc1[j]+sh1[j]);
  }
  __syncthreads();
  const int c = threadIdx.x;
  float wa2[64];
  #pragma unroll
  for (int j=0;j<64;++j) wa2[j] = Wa2[c*64+j];
  const float sc2 = stats[SCALE_A2+c], sh2 = stats[SHIFT_A2+c];
  float wt[10];
  #pragma unroll
  for (int kk=0;kk<10;++kk){
    float y=0.f;
    #pragma unroll
    for (int j=0;j<64;++j) y += wa2[j]*a1l[kk*64+j];
    wt[kk] = lrelu(y*sc2+sh2);
  }
  float mx = wt[0];
  #pragma unroll
  for (int kk=1;kk<10;++kk) mx = fmaxf(mx, wt[kk]);
  float sum = 0.f;
  #pragma unroll
  for (int kk=0;kk<10;++kk){ wt[kk] = __expf(wt[kk]-mx); sum += wt[kk]; }
  float inv = 1.f/sum;
  const float sci0 = stats[SCALE_I + 2*c], shi0 = stats[SHIFT_I + 2*c];
  const float sci1 = stats[SCALE_I + 2*c+1], shi1 = stats[SHIFT_I + 2*c+1];
  __hip_bfloat16* yb = ybuf + px*2560 + c*10;
  #pragma unroll
  for (int q = 0; q < 10; ++q){
    float v = __bfloat162float(yb[q]);
    float sc = (q < 5) ? sci0 : sci1;
    float sh = (q < 5) ? shi0 : shi1;
    yb[q] = __float2bfloat16(lrelu(v*sc+sh) * (wt[q]*inv));
  }
}

// ---------------- permute W2 to k-order (efea rows then inte rows) ----------------
__global__ __launch_bounds__(256) void k_permw2(const float* __restrict__ W2, float* __restrict__ W2p){
  const unsigned total = 256u*5120u;
  for (unsigned e = blockIdx.x*256u + threadIdx.x; e < total; e += gridDim.x*256u){
    unsigned oc = e / 5120u; unsigned k = e - oc*5120u;
    unsigned half = (k >= 2560u) ? 1u : 0u;
    unsigned kk2 = k - half*2560u;
    unsigned cch = kk2 / 10u, w = kk2 - cch*10u + half*10u;
    W2p[e] = W2[(size_t)oc*5120u + cch*20u + w];
  }
}

// ---------------- W2 GEMM: out_pre[256 x 32768]; e_fea half gathered, inte half from bf16; fused o-stats ----------------
__global__ __launch_bounds__(256) void k_w2(const float* __restrict__ xT, const int* __restrict__ idx,
                                            const __hip_bfloat16* __restrict__ inte,
                                            const float* __restrict__ W2p, float* __restrict__ outpre,
                                            float* __restrict__ stats){
  __shared__ float At[32*128];
  __shared__ float Bt[32*128];
  __shared__ int sIdx[128*10];
  const int r0 = blockIdx.x * 128;   // 2 row tiles
  const int c0 = blockIdx.y * 128;   // 256 col tiles (cols = px)
  for (int t = threadIdx.x; t < 1280; t += 256) sIdx[t] = idx[(size_t)c0*10 + t];
  const int tx = threadIdx.x & 15, ty = threadIdx.x >> 4;
  float acc[8][8];
  #pragma unroll
  for (int i=0;i<8;++i)
    #pragma unroll
    for (int j=0;j<8;++j) acc[i][j]=0.f;
  const int rowA = threadIdx.x >> 3;
  const int kqA  = threadIdx.x & 7;
  const int colB = threadIdx.x & 127;
  const int kB0  = threadIdx.x >> 7;
  const int pxg  = c0 + colB;
  const size_t selfbase = (size_t)pxg * FIN_;
  const size_t bbase = (size_t)(pxg >> 11) * N_ * FIN_;
  const __hip_bfloat16* ib = inte + (size_t)pxg*2560;

  for (int k0 = 0; k0 < 5120; k0 += 32){
    __syncthreads();
    #pragma unroll
    for (int s = 0; s < 4; ++s){
      int row = rowA + 32*s;
      const float4 v = *(const float4*)&W2p[(size_t)(r0+row)*5120 + k0 + kqA*4];
      At[(kqA*4+0)*128+row]=v.x; At[(kqA*4+1)*128+row]=v.y;
      At[(kqA*4+2)*128+row]=v.z; At[(kqA*4+3)*128+row]=v.w;
    }
    #pragma unroll
    for (int s = 0; s < 16; ++s){
      int k = kB0 + 2*s;
      int kidx = k0 + k;
      float v;
      if (kidx < 2560){
        int c = kidx / 10, w = kidx - c*10;
        if (c < 128) v = xT[selfbase + c];
        else {
          int j = sIdx[colB*10 + w];
          v = xT[bbase + (size_t)j*FIN_ + (c-128)] - xT[selfbase + (c-128)];
        }
      } else {
        v = __bfloat162float(ib[kidx - 2560]);
      }
      Bt[k*128 + colB] = v;
    }
    __syncthreads();
    #pragma unroll 8
    for (int k = 0; k < 32; ++k){
      float a[8], b[8];
      #pragma unroll
      for (int m=0;m<8;++m) a[m] = At[k*128 + ty*8 + m];
      #pragma unroll
      for (int m=0;m<8;++m) b[m] = Bt[k*128 + tx*8 + m];
      #pragma unroll
      for (int i=0;i<8;++i)
        #pragma unroll
        for (int j=0;j<8;++j) acc[i][j] += a[i]*b[j];
    }
  }
  float s_r[8], ss_r[8];
  #pragma unroll
  for (int i=0;i<8;++i){
    float s=0.f, ss=0.f;
    #pragma unroll
    for (int j=0;j<8;++j){ float v=acc[i][j]; s+=v; ss+=v*v; }
    s_r[i]=s; ss_r[i]=ss;
  }
  #pragma unroll
  for (int i=0;i<8;++i){
    size_t row = (size_t)(r0 + ty*8 + i);
    #pragma unroll
    for (int j=0;j<8;++j){
      outpre[row*32768 + c0 + tx*8 + j] = acc[i][j];
    }
  }
  __syncthreads();
  float* red = At;
  red[threadIdx.x] = 0.f;
  __syncthreads();
  #pragma unroll
  for (int i=0;i<8;++i){
    atomicAdd(&red[(ty*8+i)*2+0], s_r[i]);
    atomicAdd(&red[(ty*8+i)*2+1], ss_r[i]);
  }
  __syncthreads();
  if (threadIdx.x < 128){
    atomicAdd(&stats[SUM_O + r0 + threadIdx.x], red[threadIdx.x*2+0]);
    atomicAdd(&stats[SS_O + r0 + threadIdx.x], red[threadIdx.x*2+1]);
  }
}

// ---------------- final: bn2 + relu + reshape to [B,128,4096] ----------------
__global__ __launch_bounds__(256) void k_final(const float* __restrict__ outpre, const float* __restrict__ stats,
                                               float* __restrict__ out){
  const unsigned total = (unsigned)B_*128u*4096u;
  for (unsigned e = blockIdx.x*256u + threadIdx.x; e < total; e += gridDim.x*256u){
    unsigned b = e >> 19;
    unsigned rem = e & ((1u<<19)-1u);
    unsigned f = rem >> 12;
    unsigned m = rem & 4095u;
    unsigned half = m >> 11;
    unsigned n = m & 2047u;
    unsigned c = f*2u + half;
    float pre = outpre[(size_t)c*32768 + b*2048 + n];
    float v = pre*stats[SCALE_O+c] + stats[SHIFT_O+c];
    out[e] = fmaxf(v, 0.f);
  }
}

extern "C" void kernel_launch(void* const* d_in, const int* in_sizes, int n_in,
                              void* d_out, int out_size, void* d_ws, size_t ws_size,
                              hipStream_t stream) {
  (void)in_sizes; (void)n_in; (void)out_size;
  const float* x    = (const float*)d_in[0];
  const float* pc   = (const float*)d_in[1];
  const float* Wf   = (const float*)d_in[2];
  const float* gf   = (const float*)d_in[4];
  const float* btf  = (const float*)d_in[5];
  const float* Wx   = (const float*)d_in[6];
  const float* gx   = (const float*)d_in[8];
  const float* btx  = (const float*)d_in[9];
  const float* Wa1  = (const float*)d_in[10];
  const float* ga1  = (const float*)d_in[12];
  const float* bta1 = (const float*)d_in[13];
  const float* Wa2  = (const float*)d_in[14];
  const float* ga2  = (const float*)d_in[16];
  const float* bta2 = (const float*)d_in[17];
  const float* Wi   = (const float*)d_in[18];
  const float* gi   = (const float*)d_in[20];
  const float* bti  = (const float*)d_in[21];
  const float* W2   = (const float*)d_in[22];
  const float* g2   = (const float*)d_in[24];
  const float* bt2  = (const float*)d_in[25];
  float* out = (float*)d_out;

  char* ws = (char*)d_ws;
  float*  stats  = (float*)ws;                          //        0 ..    32768
  int*    idx    = (int*)  (ws + 32768);                //    32768 ..  1343488
  float*  sq     = (float*)(ws + 1343488);              //  1343488 ..  1605632 (uses first 131072)
  float*  wprod  = (float*)(ws + 1605632);              //  1605632 .. 22577152
  float*  xT     = (float*)(ws + 22577152);             // 22577152 .. 39354368
  float*  W2p    = (float*)(ws + 39354368);             // 39354368 .. 44597248
  float*  outpre = (float*)(ws + 44597248);             // 44597248 .. 78151680
  __hip_bfloat16* ybuf = (__hip_bfloat16*)(ws + 78151680); // 78151680 .. 245923840
  if (ws_size < 245923840ULL) {
    fprintf(stderr, "kernel_launch: ws_size %zu < required 245923840\n", ws_size);
    return;
  }

  k_zero<<<1, 256, 0, stream>>>(stats);
  k_xt<<<dim3(FIN_/32, N_/32, B_), 256, 0, stream>>>(x, xT);
  k_sq<<<(B_*N_)/256, 256, 0, stream>>>(x, sq);
  k_knn<<<dim3(N_/64, B_), 256, 0, stream>>>(x, sq, idx);
  k_permw2<<<2048, 256, 0, stream>>>(W2, W2p);

  k_fx_stats<<<(B_*N_)/256, 256, 0, stream>>>(x, pc, idx, Wf, Wx, stats);
  k_finalize<<<1, 512, 0, stream>>>(stats, SUM_F, SS_F, 16, 1.f/327680.f, gf, btf, SCALE_F, SHIFT_F);
  k_finalize<<<1, 512, 0, stream>>>(stats, SUM_X, SS_X, 16, 1.f/327680.f, gx, btx, SCALE_X, SHIFT_X);

  k_wprod<<<(B_*N_)/256, 256, 0, stream>>>(x, pc, idx, Wf, Wx, stats, wprod);
  k_a1_stats<<<512, 256, 0, stream>>>(wprod, Wa1, stats);
  k_finalize<<<1, 512, 0, stream>>>(stats, SUM_A1, SS_A1, 64, 1.f/327680.f, ga1, bta1, SCALE_A1, SHIFT_A1);

  k_a2_stats<<<512, 256, 0, stream>>>(wprod, Wa1, Wa2, stats);
  k_finalize<<<1, 512, 0, stream>>>(stats, SUM_A2, SS_A2, 256, 1.f/327680.f, ga2, bta2, SCALE_A2, SHIFT_A2);

  k_convi<<<dim3(4, 1280), 256, 0, stream>>>(xT, idx, Wi, ybuf, stats);
  k_finalize<<<1, 512, 0, stream>>>(stats, SUM_I, SS_I, 512, 1.f/163840.f, gi, bti, SCALE_I, SHIFT_I);

  k_wchain<<<B_*N_, 256, 0, stream>>>(wprod, Wa1, Wa2, stats, ybuf);

  k_w2<<<dim3(2, 256), 256, 0, stream>>>(xT, idx, ybuf, W2p, outpre, stats);
  k_finalize<<<1, 512, 0, stream>>>(stats, SUM_O, SS_O, 256, 1.f/32768.f, g2, bt2, SCALE_O, SHIFT_O);

  k_final<<<4096, 256, 0, stream>>>(outpre, stats, out);
}